// Round 4
// baseline (203.557 us; speedup 1.0000x reference)
//
#include <hip/hip_runtime.h>
#include <stdint.h>

#define V 128000
#define BROWS 256
#define CAP 2048
#define NTHREADS 1024
#define T0 16.0f

__device__ __forceinline__ unsigned rotl32(unsigned x, int d) {
  return (x << d) | (x >> (32 - d));
}

// JAX threefry2x32, key (0, 42) == jax.random.key(42).
// PARTITIONABLE path (default since JAX 0.4.30): counter = (hi32(i), lo32(i))
// = (0, i). 32-bit draw = XOR-fold of the two 32-bit output words
// (R2 tested out0 alone, R3 tested out1 alone - both failed).
__device__ __forceinline__ uint2 threefry2x32(unsigned x0, unsigned x1) {
  const unsigned k0 = 0u, k1 = 42u;
  const unsigned k2 = k0 ^ k1 ^ 0x1BD11BDAu;
  x0 += k0; x1 += k1;
#define TF_RND(r) { x0 += x1; x1 = rotl32(x1, r); x1 ^= x0; }
  TF_RND(13) TF_RND(15) TF_RND(26) TF_RND(6)
  x0 += k1; x1 += k2 + 1u;
  TF_RND(17) TF_RND(29) TF_RND(16) TF_RND(24)
  x0 += k2; x1 += k0 + 2u;
  TF_RND(13) TF_RND(15) TF_RND(26) TF_RND(6)
  x0 += k0; x1 += k1 + 3u;
  TF_RND(17) TF_RND(29) TF_RND(16) TF_RND(24)
  x0 += k1; x1 += k2 + 4u;
  TF_RND(13) TF_RND(15) TF_RND(26) TF_RND(6)
  x0 += k2; x1 += k0 + 5u;
#undef TF_RND
  return make_uint2(x0, x1);
}

// JAX gumbel: -log(-log(uniform(key, shape, minval=tiny, maxval=1)))
// uniform: f = bitcast((bits>>9)|0x3f800000) - 1.0; (1-tiny) rounds to 1.0,
// so u = max(tiny, f + tiny).
__device__ __forceinline__ float gumbel_at(unsigned flat) {
  uint2 r = threefry2x32(0u, flat);
  unsigned bits = r.x ^ r.y;  // XOR fold of both output words
  float f = __uint_as_float((bits >> 9) | 0x3F800000u) - 1.0f;
  const float TINY = 1.17549435e-38f;
  float u = fmaxf(TINY, f + TINY);
  return -logf(-logf(u));
}

// monotone float -> uint mapping (total order, sign-robust)
__device__ __forceinline__ unsigned fkey(float v) {
  unsigned u = __float_as_uint(v);
  return (u & 0x80000000u) ? ~u : (u | 0x80000000u);
}
__device__ __forceinline__ float fkey_inv(unsigned u) {
  unsigned r = (u & 0x80000000u) ? (u & 0x7FFFFFFFu) : ~u;
  return __uint_as_float(r);
}

extern "C" __global__ void __launch_bounds__(NTHREADS)
topk_topp_sample_kernel(const float* __restrict__ logits,
                        const int* __restrict__ kin,
                        const float* __restrict__ pin,
                        int* __restrict__ out) {
  const int b = blockIdx.x;
  const int tid = threadIdx.x;

  __shared__ unsigned long long cand[CAP];
  __shared__ unsigned long long topkeys[64];
  __shared__ float zpart[NTHREADS / 64];
  __shared__ float sh_sp[64];
  __shared__ float sh_g[64];
  __shared__ int sh_idx[64];
  __shared__ int cnt;
  __shared__ float shZ;

  const float4* row4 = (const float4*)(logits + (size_t)b * V);
  float T = 6.0f;  // 64th largest logit ~6.58 +/- 0.07; ~173 expected above 6.0

  if (tid == 0) cnt = 0;
  __syncthreads();

  // ---- single streaming pass: softmax denominator (fixed shift T0) + candidates
  float s = 0.0f;
  for (int i = tid; i < V / 4; i += NTHREADS) {
    float4 v = row4[i];
    s += expf(v.x - T0);
    s += expf(v.y - T0);
    s += expf(v.z - T0);
    s += expf(v.w - T0);
    int base = i * 4;
    if (v.x > T) { int pos = atomicAdd(&cnt, 1); if (pos < CAP) cand[pos] = ((unsigned long long)fkey(v.x) << 32) | (unsigned long long)(unsigned)(~(unsigned)(base + 0)); }
    if (v.y > T) { int pos = atomicAdd(&cnt, 1); if (pos < CAP) cand[pos] = ((unsigned long long)fkey(v.y) << 32) | (unsigned long long)(unsigned)(~(unsigned)(base + 1)); }
    if (v.z > T) { int pos = atomicAdd(&cnt, 1); if (pos < CAP) cand[pos] = ((unsigned long long)fkey(v.z) << 32) | (unsigned long long)(unsigned)(~(unsigned)(base + 2)); }
    if (v.w > T) { int pos = atomicAdd(&cnt, 1); if (pos < CAP) cand[pos] = ((unsigned long long)fkey(v.w) << 32) | (unsigned long long)(unsigned)(~(unsigned)(base + 3)); }
  }

  // block-reduce Z
#pragma unroll
  for (int off = 32; off > 0; off >>= 1) s += __shfl_down(s, off);
  if ((tid & 63) == 0) zpart[tid >> 6] = s;
  __syncthreads();
  if (tid == 0) {
    float z = 0.0f;
    for (int w = 0; w < NTHREADS / 64; ++w) z += zpart[w];
    shZ = z;
  }
  __syncthreads();

  // ---- fallback: adjust threshold if candidate count out of [64, CAP]
  int attempts = 0;
  while (true) {
    int n = cnt;  // uniform across block: read after barrier
    if ((n >= 64 && n <= CAP) || attempts >= 24) break;
    T = (n < 64) ? (T - 2.0f) : (T + 1.0f);
    ++attempts;
    __syncthreads();
    if (tid == 0) cnt = 0;
    __syncthreads();
    for (int i = tid; i < V / 4; i += NTHREADS) {
      float4 v = row4[i];
      int base = i * 4;
      if (v.x > T) { int pos = atomicAdd(&cnt, 1); if (pos < CAP) cand[pos] = ((unsigned long long)fkey(v.x) << 32) | (unsigned long long)(unsigned)(~(unsigned)(base + 0)); }
      if (v.y > T) { int pos = atomicAdd(&cnt, 1); if (pos < CAP) cand[pos] = ((unsigned long long)fkey(v.y) << 32) | (unsigned long long)(unsigned)(~(unsigned)(base + 1)); }
      if (v.z > T) { int pos = atomicAdd(&cnt, 1); if (pos < CAP) cand[pos] = ((unsigned long long)fkey(v.z) << 32) | (unsigned long long)(unsigned)(~(unsigned)(base + 2)); }
      if (v.w > T) { int pos = atomicAdd(&cnt, 1); if (pos < CAP) cand[pos] = ((unsigned long long)fkey(v.w) << 32) | (unsigned long long)(unsigned)(~(unsigned)(base + 3)); }
    }
    __syncthreads();
  }

  int N = cnt < CAP ? cnt : CAP;

  // ---- exact top-64 by (value desc, index asc) via rank counting.
  // Keys unique (index in low bits) -> ranks are an exact permutation.
  for (int i = tid; i < N; i += NTHREADS) {
    unsigned long long ki = cand[i];
    int rank = 0;
    for (int j = 0; j < N; ++j) rank += (cand[j] > ki) ? 1 : 0;
    if (rank < 64) topkeys[rank] = ki;
  }
  __syncthreads();

  int M = N < 64 ? N : 64;

  // ---- per-rank prob + gumbel (rank r uses flat index b*V + r)
  if (tid < M) {
    unsigned long long key = topkeys[tid];
    float v = fkey_inv((unsigned)(key >> 32));
    sh_sp[tid] = expf(v - T0) / shZ;
    sh_idx[tid] = (int)(~((unsigned)(key & 0xFFFFFFFFull)));
    sh_g[tid] = gumbel_at((unsigned)((size_t)b * V + tid));
  }
  __syncthreads();

  // ---- serial epilogue replicating reference float ops
  if (tid == 0) {
    int kk = kin[b];
    float pp = pin[b];
    float c = 0.0f, S = 0.0f;
    unsigned long long keepmask = 0ull;
    for (int r = 0; r < M; ++r) {
      float sp = sh_sp[r];
      c += sp;                         // inclusive cumsum, sequential fp32
      if (r < kk && (c - sp) < pp) {   // reference: (csum - sp) < p
        S += sp;
        keepmask |= (1ull << r);
      }
    }
    float best = -1e38f;
    int besti = sh_idx[0];
    for (int r = 0; r < M; ++r) {
      if (!(keepmask & (1ull << r))) continue;
      float lp = logf(fmaxf(sh_sp[r] / S, 1e-38f));
      float y = lp + sh_g[r];
      if (y > best) { best = y; besti = sh_idx[r]; }  // strict > = first occurrence
    }
    out[b] = besti;
  }
}

extern "C" void kernel_launch(void* const* d_in, const int* in_sizes, int n_in,
                              void* d_out, int out_size, void* d_ws, size_t ws_size,
                              hipStream_t stream) {
  const float* logits = (const float*)d_in[0];
  const int* k = (const int*)d_in[1];
  const float* p = (const float*)d_in[2];
  int* out = (int*)d_out;
  (void)in_sizes; (void)n_in; (void)out_size; (void)d_ws; (void)ws_size;
  topk_topp_sample_kernel<<<BROWS, NTHREADS, 0, stream>>>(logits, k, p, out);
}

// Round 5
// 202.571 us; speedup vs baseline: 1.0049x; 1.0049x over previous
//
#include <hip/hip_runtime.h>
#include <stdint.h>

#define V 128000
#define V4 (V / 4)
#define BROWS 256
#define CAP 2048
#define NTHREADS 1024
#define T0 16.0f

__device__ __forceinline__ unsigned rotl32(unsigned x, int d) {
  return (x << d) | (x >> (32 - d));
}

// JAX threefry2x32, key (0, 42) == jax.random.key(42).
// PARTITIONABLE path (default since JAX 0.4.30): counter = (0, i);
// 32-bit draw = XOR-fold of the two output words.  [verified: round 4 passed]
__device__ __forceinline__ uint2 threefry2x32(unsigned x0, unsigned x1) {
  const unsigned k0 = 0u, k1 = 42u;
  const unsigned k2 = k0 ^ k1 ^ 0x1BD11BDAu;
  x0 += k0; x1 += k1;
#define TF_RND(r) { x0 += x1; x1 = rotl32(x1, r); x1 ^= x0; }
  TF_RND(13) TF_RND(15) TF_RND(26) TF_RND(6)
  x0 += k1; x1 += k2 + 1u;
  TF_RND(17) TF_RND(29) TF_RND(16) TF_RND(24)
  x0 += k2; x1 += k0 + 2u;
  TF_RND(13) TF_RND(15) TF_RND(26) TF_RND(6)
  x0 += k0; x1 += k1 + 3u;
  TF_RND(17) TF_RND(29) TF_RND(16) TF_RND(24)
  x0 += k1; x1 += k2 + 4u;
  TF_RND(13) TF_RND(15) TF_RND(26) TF_RND(6)
  x0 += k2; x1 += k0 + 5u;
#undef TF_RND
  return make_uint2(x0, x1);
}

__device__ __forceinline__ float gumbel_at(unsigned flat) {
  uint2 r = threefry2x32(0u, flat);
  unsigned bits = r.x ^ r.y;  // XOR fold
  float f = __uint_as_float((bits >> 9) | 0x3F800000u) - 1.0f;
  const float TINY = 1.17549435e-38f;
  float u = fmaxf(TINY, f + TINY);
  return -logf(-logf(u));
}

// monotone float -> uint mapping (total order, sign-robust)
__device__ __forceinline__ unsigned fkey(float v) {
  unsigned u = __float_as_uint(v);
  return (u & 0x80000000u) ? ~u : (u | 0x80000000u);
}
__device__ __forceinline__ float fkey_inv(unsigned u) {
  unsigned r = (u & 0x80000000u) ? (u & 0x7FFFFFFFu) : ~u;
  return __uint_as_float(r);
}

extern "C" __global__ void __launch_bounds__(NTHREADS)
topk_topp_sample_kernel(const float* __restrict__ logits,
                        const int* __restrict__ kin,
                        const float* __restrict__ pin,
                        int* __restrict__ out) {
  const int b = blockIdx.x;
  const int tid = threadIdx.x;

  __shared__ unsigned long long cand[CAP];
  __shared__ unsigned long long topkeys[64];
  __shared__ float zpart[NTHREADS / 64];
  __shared__ float sh_sp[64];
  __shared__ float sh_g[64];
  __shared__ int sh_idx[64];
  __shared__ int cnt;
  __shared__ float shZ;

  const float4* row4 = (const float4*)(logits + (size_t)b * V);
  float T = 6.0f;  // 64th largest logit ~6.58; ~173 expected above 6.0

  if (tid == 0) cnt = 0;
  __syncthreads();

  // ---- streaming pass: Z via native v_exp_f32 (Z needs only ~3 digits:
  // it cancels in log(sp/S); top-p mask has >=2.5x slack) + candidate collect.
  const float L2E = 1.44269504088896340736f;
  const float NB  = -16.0f * 1.44269504088896340736f;
  float zs0 = 0.0f, zs1 = 0.0f;

#define PROCV(vv, ii)                                                          \
  {                                                                            \
    float4 v = (vv);                                                           \
    zs0 += __builtin_amdgcn_exp2f(__builtin_fmaf(v.x, L2E, NB));               \
    zs1 += __builtin_amdgcn_exp2f(__builtin_fmaf(v.y, L2E, NB));               \
    zs0 += __builtin_amdgcn_exp2f(__builtin_fmaf(v.z, L2E, NB));               \
    zs1 += __builtin_amdgcn_exp2f(__builtin_fmaf(v.w, L2E, NB));               \
    int base = (ii) * 4;                                                       \
    if (v.x > T) { int pos = atomicAdd(&cnt, 1); if (pos < CAP) cand[pos] = ((unsigned long long)fkey(v.x) << 32) | (unsigned long long)(unsigned)(~(unsigned)(base + 0)); } \
    if (v.y > T) { int pos = atomicAdd(&cnt, 1); if (pos < CAP) cand[pos] = ((unsigned long long)fkey(v.y) << 32) | (unsigned long long)(unsigned)(~(unsigned)(base + 1)); } \
    if (v.z > T) { int pos = atomicAdd(&cnt, 1); if (pos < CAP) cand[pos] = ((unsigned long long)fkey(v.z) << 32) | (unsigned long long)(unsigned)(~(unsigned)(base + 2)); } \
    if (v.w > T) { int pos = atomicAdd(&cnt, 1); if (pos < CAP) cand[pos] = ((unsigned long long)fkey(v.w) << 32) | (unsigned long long)(unsigned)(~(unsigned)(base + 3)); } \
  }

  {
    int i = tid;
    for (; i + NTHREADS < V4; i += 2 * NTHREADS) {
      float4 a = row4[i];               // both loads issued before first use
      float4 c = row4[i + NTHREADS];
      PROCV(a, i);
      PROCV(c, i + NTHREADS);
    }
    if (i < V4) {
      float4 a = row4[i];
      PROCV(a, i);
    }
  }
  float s = zs0 + zs1;

  // block-reduce Z
#pragma unroll
  for (int off = 32; off > 0; off >>= 1) s += __shfl_down(s, off);
  if ((tid & 63) == 0) zpart[tid >> 6] = s;
  __syncthreads();
  if (tid == 0) {
    float z = 0.0f;
    for (int w = 0; w < NTHREADS / 64; ++w) z += zpart[w];
    shZ = z;
  }
  __syncthreads();

  // ---- fallback: adjust threshold if candidate count out of [64, CAP]
  int attempts = 0;
  while (true) {
    int n = cnt;  // uniform across block: read after barrier
    if ((n >= 64 && n <= CAP) || attempts >= 24) break;
    T = (n < 64) ? (T - 2.0f) : (T + 1.0f);
    ++attempts;
    __syncthreads();
    if (tid == 0) cnt = 0;
    __syncthreads();
    for (int i = tid; i < V4; i += NTHREADS) {
      float4 v = row4[i];
      int base = i * 4;
      if (v.x > T) { int pos = atomicAdd(&cnt, 1); if (pos < CAP) cand[pos] = ((unsigned long long)fkey(v.x) << 32) | (unsigned long long)(unsigned)(~(unsigned)(base + 0)); }
      if (v.y > T) { int pos = atomicAdd(&cnt, 1); if (pos < CAP) cand[pos] = ((unsigned long long)fkey(v.y) << 32) | (unsigned long long)(unsigned)(~(unsigned)(base + 1)); }
      if (v.z > T) { int pos = atomicAdd(&cnt, 1); if (pos < CAP) cand[pos] = ((unsigned long long)fkey(v.z) << 32) | (unsigned long long)(unsigned)(~(unsigned)(base + 2)); }
      if (v.w > T) { int pos = atomicAdd(&cnt, 1); if (pos < CAP) cand[pos] = ((unsigned long long)fkey(v.w) << 32) | (unsigned long long)(unsigned)(~(unsigned)(base + 3)); }
    }
    __syncthreads();
  }

  int N = cnt < CAP ? cnt : CAP;

  // ---- exact top-64 by (value desc, index asc) via rank counting.
  for (int i = tid; i < N; i += NTHREADS) {
    unsigned long long ki = cand[i];
    int rank = 0;
    for (int j = 0; j < N; ++j) rank += (cand[j] > ki) ? 1 : 0;
    if (rank < 64) topkeys[rank] = ki;
  }
  __syncthreads();

  int M = N < 64 ? N : 64;

  // ---- per-rank prob + gumbel (rank r uses flat index b*V + r)
  // accurate expf here (64 calls, matches the passing round-4 epilogue)
  if (tid < M) {
    unsigned long long key = topkeys[tid];
    float v = fkey_inv((unsigned)(key >> 32));
    sh_sp[tid] = expf(v - T0) / shZ;
    sh_idx[tid] = (int)(~((unsigned)(key & 0xFFFFFFFFull)));
    sh_g[tid] = gumbel_at((unsigned)((size_t)b * V + tid));
  }
  __syncthreads();

  // ---- serial epilogue replicating reference float ops
  if (tid == 0) {
    int kk = kin[b];
    float pp = pin[b];
    float c = 0.0f, S = 0.0f;
    unsigned long long keepmask = 0ull;
    for (int r = 0; r < M; ++r) {
      float sp = sh_sp[r];
      c += sp;                         // inclusive cumsum, sequential fp32
      if (r < kk && (c - sp) < pp) {   // reference: (csum - sp) < p
        S += sp;
        keepmask |= (1ull << r);
      }
    }
    float best = -1e38f;
    int besti = sh_idx[0];
    for (int r = 0; r < M; ++r) {
      if (!(keepmask & (1ull << r))) continue;
      float lp = logf(fmaxf(sh_sp[r] / S, 1e-38f));
      float y = lp + sh_g[r];
      if (y > best) { best = y; besti = sh_idx[r]; }  // strict > = first occurrence
    }
    out[b] = besti;
  }
}

extern "C" void kernel_launch(void* const* d_in, const int* in_sizes, int n_in,
                              void* d_out, int out_size, void* d_ws, size_t ws_size,
                              hipStream_t stream) {
  const float* logits = (const float*)d_in[0];
  const int* k = (const int*)d_in[1];
  const float* p = (const float*)d_in[2];
  int* out = (int*)d_out;
  (void)in_sizes; (void)n_in; (void)out_size; (void)d_ws; (void)ws_size;
  topk_topp_sample_kernel<<<BROWS, NTHREADS, 0, stream>>>(logits, k, p, out);
}